// Round 1
// baseline (72.198 us; speedup 1.0000x reference)
//
#include <hip/hip_runtime.h>
#include <hip/hip_bf16.h>

#define BDIM 4096
#define DDIM 512
#define NSPLIT 8
#define COLS_PER_SPLIT (BDIM / NSPLIT)   // 512
#define NB 32                            // cols staged per chunk
#define ROWS_PER_BLOCK 64                // 4 waves x 16 rows
#define KSTEPS (DDIM / 32)               // 16 mfma k-steps
#define LDB 520                          // padded LDS row stride (bf16 elems): +16B -> 2-way bank alias (free)

typedef __bf16 bf16x8 __attribute__((ext_vector_type(8)));
typedef float f32x4 __attribute__((ext_vector_type(4)));
typedef unsigned short ushort_t;

__device__ inline ushort_t f2bf(float f) {
  __hip_bfloat16 h = __float2bfloat16(f);
  return *reinterpret_cast<ushort_t*>(&h);
}

// ---------------- kernel 1: L2-normalize rows, emit bf16 ----------------
__global__ __launch_bounds__(256) void norm_kernel(const float* __restrict__ x,
                                                   ushort_t* __restrict__ e) {
  const int row  = blockIdx.x * 4 + (threadIdx.x >> 6);
  const int lane = threadIdx.x & 63;
  const float4* xr = reinterpret_cast<const float4*>(x + (size_t)row * DDIM);
  float4 v0 = xr[lane];
  float4 v1 = xr[lane + 64];
  float ss = v0.x*v0.x + v0.y*v0.y + v0.z*v0.z + v0.w*v0.w
           + v1.x*v1.x + v1.y*v1.y + v1.z*v1.z + v1.w*v1.w;
#pragma unroll
  for (int off = 32; off >= 1; off >>= 1) ss += __shfl_xor(ss, off);
  const float inv = 1.0f / fmaxf(sqrtf(ss), 1e-12f);

  ushort4 p0, p1;
  p0.x = f2bf(v0.x * inv); p0.y = f2bf(v0.y * inv);
  p0.z = f2bf(v0.z * inv); p0.w = f2bf(v0.w * inv);
  p1.x = f2bf(v1.x * inv); p1.y = f2bf(v1.y * inv);
  p1.z = f2bf(v1.z * inv); p1.w = f2bf(v1.w * inv);
  ushort4* er = reinterpret_cast<ushort4*>(e + (size_t)row * DDIM);
  er[lane]      = p0;
  er[lane + 64] = p1;
}

// ------- kernel 2: fused S = E E^T tile + masked row min/max reduce -------
__global__ __launch_bounds__(256) void gemm_reduce_kernel(
    const ushort_t* __restrict__ e, const int* __restrict__ labels,
    float* __restrict__ pminpos, float* __restrict__ pmaxneg) {
  __shared__ ushort_t Blds[NB * LDB];
  __shared__ int Llds[NB];

  const int rowblk = blockIdx.x;          // 0..63
  const int split  = blockIdx.y;          // 0..7
  const int tid  = threadIdx.x;
  const int wave = tid >> 6;              // 0..3
  const int lane = tid & 63;
  const int l15  = lane & 15;
  const int lhi  = lane >> 4;             // 0..3

  const int rowbase = rowblk * ROWS_PER_BLOCK + wave * 16;
  const int colbase = split * COLS_PER_SPLIT;

  // A fragments resident in registers: lane holds row (rowbase+l15), k = ks*32 + lhi*8 + [0..8)
  bf16x8 afrag[KSTEPS];
  {
    const ushort_t* arow = e + (size_t)(rowbase + l15) * DDIM + lhi * 8;
#pragma unroll
    for (int k = 0; k < KSTEPS; ++k)
      afrag[k] = *reinterpret_cast<const bf16x8*>(arow + k * 32);
  }

  int li[4];
#pragma unroll
  for (int r = 0; r < 4; ++r) li[r] = labels[rowbase + lhi * 4 + r];

  float minpos[4], maxneg[4];
#pragma unroll
  for (int r = 0; r < 4; ++r) { minpos[r] = 1e30f; maxneg[r] = -1e30f; }

  const int nchunks = COLS_PER_SPLIT / NB;  // 16
  for (int c = 0; c < nchunks; ++c) {
    const int jbase = colbase + c * NB;
    __syncthreads();
    // stage NB x DDIM bf16 chunk (padded rows)
#pragma unroll
    for (int it = 0; it < (NB * DDIM / 8) / 256; ++it) {  // 8 iters
      int idx = tid + it * 256;           // 0..2047
      int jr  = idx >> 6;                 // col row 0..31
      int c16 = idx & 63;                 // 16B chunk in row
      bf16x8 v = *reinterpret_cast<const bf16x8*>(
          e + (size_t)(jbase + jr) * DDIM + c16 * 8);
      *reinterpret_cast<bf16x8*>(&Blds[jr * LDB + c16 * 8]) = v;
    }
    if (tid < NB) Llds[tid] = labels[jbase + tid];
    __syncthreads();

#pragma unroll
    for (int js = 0; js < 2; ++js) {
      f32x4 acc = {0.f, 0.f, 0.f, 0.f};
      const ushort_t* bbase = &Blds[(js * 16 + l15) * LDB + lhi * 8];
#pragma unroll
      for (int k = 0; k < KSTEPS; ++k) {
        bf16x8 bfrag = *reinterpret_cast<const bf16x8*>(bbase + k * 32);
        acc = __builtin_amdgcn_mfma_f32_16x16x32_bf16(afrag[k], bfrag, acc, 0, 0, 0);
      }
      const int j  = jbase + js * 16 + l15;
      const int lj = Llds[js * 16 + l15];
#pragma unroll
      for (int r = 0; r < 4; ++r) {
        const int i = rowbase + lhi * 4 + r;
        const float s = acc[r];
        if (li[r] == lj) {
          if (i != j) minpos[r] = fminf(minpos[r], s);
        } else {
          maxneg[r] = fmaxf(maxneg[r], s);
        }
      }
    }
  }

  // reduce across the 16 lanes (same lhi) covering different cols of same rows
#pragma unroll
  for (int off = 1; off < 16; off <<= 1) {
#pragma unroll
    for (int r = 0; r < 4; ++r) {
      minpos[r] = fminf(minpos[r], __shfl_xor(minpos[r], off));
      maxneg[r] = fmaxf(maxneg[r], __shfl_xor(maxneg[r], off));
    }
  }
  if (l15 == 0) {
#pragma unroll
    for (int r = 0; r < 4; ++r) {
      const int i = rowbase + lhi * 4 + r;
      pminpos[split * BDIM + i] = minpos[r];
      pmaxneg[split * BDIM + i] = maxneg[r];
    }
  }
}

// ---------------- kernel 3: combine splits -> scalar loss ----------------
__global__ __launch_bounds__(1024) void finalize_kernel(
    const float* __restrict__ pminpos, const float* __restrict__ pmaxneg,
    float* __restrict__ out) {
  const int tid = threadIdx.x;
  float sum = 0.f;
  int cnt = 0;
  for (int row = tid; row < BDIM; row += 1024) {
    float mp = 1e30f, mn = -1e30f;
#pragma unroll
    for (int s = 0; s < NSPLIT; ++s) {
      mp = fminf(mp, pminpos[s * BDIM + row]);
      mn = fmaxf(mn, pmaxneg[s * BDIM + row]);
    }
    if (mp < 1e29f && mn > -1e29f) {
      // hp - hn + margin = (1-mp) - (1-mn) + 0.2 = mn - mp + 0.2
      sum += fmaxf(0.f, mn - mp + 0.2f);
      cnt += 1;
    }
  }
#pragma unroll
  for (int off = 32; off >= 1; off >>= 1) {
    sum += __shfl_xor(sum, off);
    cnt += __shfl_xor(cnt, off);
  }
  __shared__ float wsum[16];
  __shared__ int   wcnt[16];
  const int wv = tid >> 6, ln = tid & 63;
  if (ln == 0) { wsum[wv] = sum; wcnt[wv] = cnt; }
  __syncthreads();
  if (tid == 0) {
    float S = 0.f; int C = 0;
    for (int w = 0; w < 16; ++w) { S += wsum[w]; C += wcnt[w]; }
    out[0] = S / (float)(C > 0 ? C : 1);
  }
}

extern "C" void kernel_launch(void* const* d_in, const int* in_sizes, int n_in,
                              void* d_out, int out_size, void* d_ws, size_t ws_size,
                              hipStream_t stream) {
  const float* x      = (const float*)d_in[0];
  const int*   labels = (const int*)d_in[1];
  float* out = (float*)d_out;

  char* ws = (char*)d_ws;
  ushort_t* e     = (ushort_t*)ws;                              // 4 MB bf16 E
  float* pminpos  = (float*)(ws + (size_t)BDIM * DDIM * 2);     // [8][4096]
  float* pmaxneg  = pminpos + NSPLIT * BDIM;                    // [8][4096]

  norm_kernel<<<BDIM / 4, 256, 0, stream>>>(x, e);
  dim3 g(BDIM / ROWS_PER_BLOCK, NSPLIT);
  gemm_reduce_kernel<<<g, 256, 0, stream>>>(e, labels, pminpos, pmaxneg);
  finalize_kernel<<<1, 1024, 0, stream>>>(pminpos, pmaxneg, out);
}

// Round 2
// 52.822 us; speedup vs baseline: 1.3668x; 1.3668x over previous
//
#include <hip/hip_runtime.h>
#include <hip/hip_bf16.h>

#define BDIM 4096
#define DDIM 512
#define NSPLIT 16
#define CPS (BDIM / NSPLIT)      // 256 cols per split
#define NB 32                    // cols staged per chunk (32 KB)
#define NCHUNK (CPS / NB)        // 8
#define KS (DDIM / 16)           // 32 mfma k-steps (K=16 each)
#define RPW 32                   // rows per wave (A register-resident)
#define RPB 128                  // rows per block (4 waves)

typedef __bf16 bf16x8 __attribute__((ext_vector_type(8)));
typedef float f32x16 __attribute__((ext_vector_type(16)));
typedef unsigned short ushort_t;

__device__ inline ushort_t f2bf(float f) {
  __hip_bfloat16 h = __float2bfloat16(f);
  return *reinterpret_cast<ushort_t*>(&h);
}

// ---------------- kernel 1: L2-normalize rows, emit bf16 ----------------
__global__ __launch_bounds__(256) void norm_kernel(const float* __restrict__ x,
                                                   ushort_t* __restrict__ e) {
  const int row  = blockIdx.x * 4 + (threadIdx.x >> 6);
  const int lane = threadIdx.x & 63;
  const float4* xr = reinterpret_cast<const float4*>(x + (size_t)row * DDIM);
  float4 v0 = xr[lane];
  float4 v1 = xr[lane + 64];
  float ss = v0.x*v0.x + v0.y*v0.y + v0.z*v0.z + v0.w*v0.w
           + v1.x*v1.x + v1.y*v1.y + v1.z*v1.z + v1.w*v1.w;
#pragma unroll
  for (int off = 32; off >= 1; off >>= 1) ss += __shfl_xor(ss, off);
  const float inv = 1.0f / fmaxf(sqrtf(ss), 1e-12f);

  ushort4 p0, p1;
  p0.x = f2bf(v0.x * inv); p0.y = f2bf(v0.y * inv);
  p0.z = f2bf(v0.z * inv); p0.w = f2bf(v0.w * inv);
  p1.x = f2bf(v1.x * inv); p1.y = f2bf(v1.y * inv);
  p1.z = f2bf(v1.z * inv); p1.w = f2bf(v1.w * inv);
  ushort4* er = reinterpret_cast<ushort4*>(e + (size_t)row * DDIM);
  er[lane]      = p0;
  er[lane + 64] = p1;
}

// ------- kernel 2: fused S = E E^T tile + masked row min/max reduce -------
// Stage chunk (ch) into LDS buffer (bi): linear dest via global_load_lds,
// inverse-swizzled global source so LDS holds the swizzled layout (rule #21).
#define STAGE(bi, ch)                                                          \
  do {                                                                         \
    const char* gsrc =                                                         \
        (const char*)e + ((size_t)(colbase + (ch) * NB)) * (DDIM * 2);         \
    _Pragma("unroll")                                                          \
    for (int q = 0; q < 8; ++q) {                                              \
      const int cc = wave * 8 + q;                                             \
      const int gb = cc * 1024 + ((lane * 16) ^ ((cc & 7) << 4));              \
      __builtin_amdgcn_global_load_lds(                                        \
          (const __attribute__((address_space(1))) void*)(gsrc + gb),          \
          (__attribute__((address_space(3))) void*)(&Blds[bi][cc * 1024]),     \
          16, 0, 0);                                                           \
    }                                                                          \
  } while (0)

__global__ __launch_bounds__(256, 2) void gemm_reduce_kernel(
    const ushort_t* __restrict__ e, const int* __restrict__ labels,
    float* __restrict__ pminpos, float* __restrict__ pmaxneg) {
  __shared__ __align__(16) char Blds[2][NB * 1024];

  const int tid  = threadIdx.x;
  const int wave = tid >> 6;
  const int lane = tid & 63;
  const int c    = lane & 31;   // local col in tile; also local A-row index
  const int hi   = lane >> 5;   // 0/1
  const int swz  = (c & 7) << 4;

  const int rowbase = blockIdx.x * RPB + wave * RPW;
  const int colbase = blockIdx.y * CPS;

  // A fragments resident in registers: lane holds row (rowbase+c),
  // k = ks*16 + hi*8 + [0..8)
  bf16x8 afrag[KS];
  {
    const ushort_t* aptr = e + (size_t)(rowbase + c) * DDIM + hi * 8;
#pragma unroll
    for (int ks = 0; ks < KS; ++ks)
      afrag[ks] = *reinterpret_cast<const bf16x8*>(aptr + ks * 16);
  }

  // labels of the 16 output rows this lane owns (C/D layout of 32x32 mfma)
  int lrow[16];
#pragma unroll
  for (int r = 0; r < 16; ++r)
    lrow[r] = labels[rowbase + (r & 3) + 8 * (r >> 2) + 4 * hi];

  float minpos[16], maxneg[16];
#pragma unroll
  for (int r = 0; r < 16; ++r) { minpos[r] = 1e30f; maxneg[r] = -1e30f; }

  STAGE(0, 0);
  __syncthreads();

  for (int ch = 0; ch < NCHUNK; ++ch) {
    if (ch + 1 < NCHUNK) STAGE((ch + 1) & 1, ch + 1);  // async prefetch

    const int lj = labels[colbase + ch * NB + c];
    const char* bb = Blds[ch & 1] + c * 1024;

    f32x16 acc = {0.f, 0.f, 0.f, 0.f, 0.f, 0.f, 0.f, 0.f,
                  0.f, 0.f, 0.f, 0.f, 0.f, 0.f, 0.f, 0.f};
#pragma unroll
    for (int ks = 0; ks < KS; ++ks) {
      bf16x8 bfrag = *reinterpret_cast<const bf16x8*>(
          bb + ((ks * 32 + hi * 16) ^ swz));
      acc = __builtin_amdgcn_mfma_f32_32x32x16_bf16(afrag[ks], bfrag, acc, 0, 0, 0);
    }

    const int j = colbase + ch * NB + c;
#pragma unroll
    for (int r = 0; r < 16; ++r) {
      const int i = rowbase + (r & 3) + 8 * (r >> 2) + 4 * hi;
      const float s = acc[r];
      if (lrow[r] == lj) {
        if (i != j) minpos[r] = fminf(minpos[r], s);
      } else {
        maxneg[r] = fmaxf(maxneg[r], s);
      }
    }
    __syncthreads();  // staged (ch+1) complete (vmcnt drain) + buffer release
  }

  // reduce across the 32 lanes (same hi) holding different cols of same rows
#pragma unroll
  for (int off = 1; off < 32; off <<= 1) {
#pragma unroll
    for (int r = 0; r < 16; ++r) {
      minpos[r] = fminf(minpos[r], __shfl_xor(minpos[r], off));
      maxneg[r] = fmaxf(maxneg[r], __shfl_xor(maxneg[r], off));
    }
  }
  if (c == 0) {
#pragma unroll
    for (int r = 0; r < 16; ++r) {
      const int i = rowbase + (r & 3) + 8 * (r >> 2) + 4 * hi;
      pminpos[blockIdx.y * BDIM + i] = minpos[r];
      pmaxneg[blockIdx.y * BDIM + i] = maxneg[r];
    }
  }
}

// ---------------- kernel 3: combine splits -> scalar loss ----------------
__global__ __launch_bounds__(1024) void finalize_kernel(
    const float* __restrict__ pminpos, const float* __restrict__ pmaxneg,
    float* __restrict__ out) {
  const int tid = threadIdx.x;
  float sum = 0.f;
  int cnt = 0;
  for (int row = tid; row < BDIM; row += 1024) {
    float mp = 1e30f, mn = -1e30f;
#pragma unroll
    for (int s = 0; s < NSPLIT; ++s) {
      mp = fminf(mp, pminpos[s * BDIM + row]);
      mn = fmaxf(mn, pmaxneg[s * BDIM + row]);
    }
    if (mp < 1e29f && mn > -1e29f) {
      // hp - hn + margin = (1-mp) - (1-mn) + 0.2 = mn - mp + 0.2
      sum += fmaxf(0.f, mn - mp + 0.2f);
      cnt += 1;
    }
  }
#pragma unroll
  for (int off = 32; off >= 1; off >>= 1) {
    sum += __shfl_xor(sum, off);
    cnt += __shfl_xor(cnt, off);
  }
  __shared__ float wsum[16];
  __shared__ int   wcnt[16];
  const int wv = tid >> 6, ln = tid & 63;
  if (ln == 0) { wsum[wv] = sum; wcnt[wv] = cnt; }
  __syncthreads();
  if (tid == 0) {
    float S = 0.f; int C = 0;
    for (int w = 0; w < 16; ++w) { S += wsum[w]; C += wcnt[w]; }
    out[0] = S / (float)(C > 0 ? C : 1);
  }
}

extern "C" void kernel_launch(void* const* d_in, const int* in_sizes, int n_in,
                              void* d_out, int out_size, void* d_ws, size_t ws_size,
                              hipStream_t stream) {
  const float* x      = (const float*)d_in[0];
  const int*   labels = (const int*)d_in[1];
  float* out = (float*)d_out;

  char* ws = (char*)d_ws;
  ushort_t* e     = (ushort_t*)ws;                              // 4 MB bf16 E
  float* pminpos  = (float*)(ws + (size_t)BDIM * DDIM * 2);     // [16][4096]
  float* pmaxneg  = pminpos + NSPLIT * BDIM;                    // [16][4096]

  norm_kernel<<<BDIM / 4, 256, 0, stream>>>(x, e);
  dim3 g(BDIM / RPB, NSPLIT);
  gemm_reduce_kernel<<<g, 256, 0, stream>>>(e, labels, pminpos, pmaxneg);
  finalize_kernel<<<1, 1024, 0, stream>>>(pminpos, pmaxneg, out);
}